// Round 1
// baseline (439.391 us; speedup 1.0000x reference)
//
#include <hip/hip_runtime.h>
#include <hip/hip_bf16.h>
#include <cstdint>

#define DEV __device__ __forceinline__

typedef __attribute__((ext_vector_type(8))) __bf16 bf16x8;
typedef __attribute__((ext_vector_type(4))) float f32x4;

DEV ushort f2bf(float f){
  uint32_t u = __builtin_bit_cast(uint32_t, f);
  u += 0x7fffu + ((u >> 16) & 1u);   // RNE
  return (ushort)(u >> 16);
}

DEV void gll16(const void* g, void* l){
  __builtin_amdgcn_global_load_lds((const __attribute__((address_space(1))) void*)g,
                                   (__attribute__((address_space(3))) void*)l, 16, 0, 0);
}

// stage a 128x32 bf16 tile (128 rows of 32 contiguous bf16 from a row-major [*, ldk] matrix)
// into linear LDS [128][32]. 256 threads, 2 global_load_lds_dwordx4 calls each.
DEV void stage128x32(const ushort* gbase, int ldk, ushort* lds, int tid){
  int w = tid >> 6;
#pragma unroll
  for (int q = 0; q < 2; ++q){
    int chunk = q*256 + tid;          // 16B chunk index, 512 total
    int r  = chunk >> 2;              // row (64B per row)
    int cb = (chunk & 3) << 4;        // byte offset within row
    const char* g = (const char*)gbase + (size_t)r*(size_t)(ldk*2) + cb;
    ushort* l = lds + (size_t)(q*256 + w*64)*8;   // wave-uniform base; HW adds lane*16B
    gll16(g, l);
  }
}

// C[M,N] = A[M,K] @ Bt[N,K]^T  (bf16 in, f32 acc), 128x128 tile, 4 waves, 4x4 MFMA tiles/wave.
// MODE 0: C_bf16 = acc + bias[col]                       (projections)
// MODE 1: C_bf16 = exp(acc*scale); f32 partial row sums  (scores)
// MODE 2: C_f32  = acc / denom[row]                      (PV)
template<int MODE>
__global__ __launch_bounds__(256) void gemm_bt(
    const ushort* __restrict__ A, const ushort* __restrict__ Bt,
    const float* __restrict__ bias,
    ushort* __restrict__ Cb, float* __restrict__ Cf,
    int M, int N, int K,
    size_t sA, size_t sB, size_t sC,
    float scale, float* __restrict__ partial,
    const float* __restrict__ denom)
{
  __shared__ ushort As[128*32];
  __shared__ ushort Bs[128*32];
  int tid  = threadIdx.x;
  int lane = tid & 63, w = tid >> 6;
  int wr = w >> 1, wc = w & 1;
  int bm = blockIdx.x, bn = blockIdx.y, bz = blockIdx.z;
  const ushort* Ab = A + (size_t)bz*sA + (size_t)bm*128*(size_t)K;
  const ushort* Bb = Bt + (size_t)bz*sB + (size_t)bn*128*(size_t)K;

  f32x4 acc[4][4];
  const f32x4 z = {0.f, 0.f, 0.f, 0.f};
#pragma unroll
  for (int m = 0; m < 4; m++)
#pragma unroll
    for (int n = 0; n < 4; n++) acc[m][n] = z;

  int lr = lane & 15;          // fragment row/col within 16
  int lk = (lane >> 4) << 3;   // k-offset of this lane's 8 elements
  int fq = lane >> 4;

  for (int k0 = 0; k0 < K; k0 += 32){
    stage128x32(Ab + k0, K, As, tid);
    stage128x32(Bb + k0, K, Bs, tid);
    __syncthreads();           // compiler drains vmcnt before s_barrier
    bf16x8 af[4], bfv[4];
#pragma unroll
    for (int m = 0; m < 4; m++)
      af[m] = *(const bf16x8*)&As[(wr*64 + m*16 + lr)*32 + lk];
#pragma unroll
    for (int n = 0; n < 4; n++)
      bfv[n] = *(const bf16x8*)&Bs[(wc*64 + n*16 + lr)*32 + lk];
#pragma unroll
    for (int m = 0; m < 4; m++)
#pragma unroll
      for (int n = 0; n < 4; n++)
        acc[m][n] = __builtin_amdgcn_mfma_f32_16x16x32_bf16(af[m], bfv[n], acc[m][n], 0, 0, 0);
    __syncthreads();
  }

  int rbase = bm*128 + wr*64;
  int cbase = bn*128 + wc*64;

  if (MODE == 0){
    ushort* dst = Cb + (size_t)bz*sC;
#pragma unroll
    for (int m = 0; m < 4; m++){
      int r0 = rbase + m*16 + (fq << 2);
#pragma unroll
      for (int n = 0; n < 4; n++){
        int c = cbase + n*16 + lr;
        float bv = bias[c];
#pragma unroll
        for (int i = 0; i < 4; i++)
          dst[(size_t)(r0 + i)*N + c] = f2bf(acc[m][n][i] + bv);
      }
    }
  } else if (MODE == 1){
    ushort* dst = Cb + (size_t)bz*sC;
    int nch = N >> 6;   // 64-col chunks
#pragma unroll
    for (int m = 0; m < 4; m++){
      int r0 = rbase + m*16 + (fq << 2);
#pragma unroll
      for (int i = 0; i < 4; i++){
        int r = r0 + i;
        float rs = 0.f;
#pragma unroll
        for (int n = 0; n < 4; n++){
          int c = cbase + n*16 + lr;
          float v = expf(acc[m][n][i] * scale);
          dst[(size_t)r*N + c] = f2bf(v);
          rs += v;            // f32 sum from f32 exp values (NOT bf16-rounded)
        }
        rs += __shfl_xor(rs, 1);
        rs += __shfl_xor(rs, 2);
        rs += __shfl_xor(rs, 4);
        rs += __shfl_xor(rs, 8);
        if (lr == 0)
          partial[((size_t)bz*M + r)*nch + (bn*2 + wc)] = rs;   // single writer, deterministic
      }
    }
  } else { // MODE 2
    float* dst = Cf + (size_t)bz*sC;
#pragma unroll
    for (int m = 0; m < 4; m++){
      int r0 = rbase + m*16 + (fq << 2);
#pragma unroll
      for (int i = 0; i < 4; i++){
        int r = r0 + i;
        float inv = 1.0f / denom[(size_t)bz*M + r];
#pragma unroll
        for (int n = 0; n < 4; n++){
          int c = cbase + n*16 + lr;
          dst[(size_t)r*N + c] = acc[m][n][i] * inv;
        }
      }
    }
  }
}

__global__ void denom_k(const float* __restrict__ partial, const int* __restrict__ alen,
                        float* __restrict__ denom, int L, int nch){
  int i = blockIdx.x*blockDim.x + threadIdx.x;   // over B*L
  int b = i / L;
  const float* p = partial + (size_t)i*nch;
  float s = 0.f;
  for (int j = 0; j < nch; j++) s += p[j];
  denom[i] = s - (float)(L - alen[b]);
}

__global__ void cvt_f32_bf16(const float* __restrict__ in, ushort* __restrict__ out, long n4){
  long i = (long)blockIdx.x*blockDim.x + threadIdx.x;
  if (i >= n4) return;
  float4 f = ((const float4*)in)[i];
  ushort4 u;
  u.x = f2bf(f.x); u.y = f2bf(f.y); u.z = f2bf(f.z); u.w = f2bf(f.w);
  ((ushort4*)out)[i] = u;
}

// out[C,R] = in[R,C]^T with f32->bf16 convert. block (32,8)
__global__ __launch_bounds__(256) void transpose_f32_bf16(
    const float* __restrict__ in, ushort* __restrict__ out, int R, int C){
  __shared__ ushort t[32][33];
  int tx = threadIdx.x, ty = threadIdx.y;
  int c0 = blockIdx.x*32, r0 = blockIdx.y*32;
#pragma unroll
  for (int i = 0; i < 4; i++)
    t[ty + i*8][tx] = f2bf(in[(size_t)(r0 + ty + i*8)*C + c0 + tx]);
  __syncthreads();
#pragma unroll
  for (int i = 0; i < 4; i++)
    out[(size_t)(c0 + ty + i*8)*R + r0 + tx] = t[tx][ty + i*8];
}

// batched bf16 transpose: out[b][C,R] = in[b][R,C]^T. block (32,8), grid (C/32, R/32, B)
__global__ __launch_bounds__(256) void transpose_bf16(
    const ushort* __restrict__ in, ushort* __restrict__ out,
    int R, int C, size_t sIn, size_t sOut){
  __shared__ ushort t[32][33];
  const ushort* src = in + (size_t)blockIdx.z*sIn;
  ushort* dst = out + (size_t)blockIdx.z*sOut;
  int tx = threadIdx.x, ty = threadIdx.y;
  int c0 = blockIdx.x*32, r0 = blockIdx.y*32;
#pragma unroll
  for (int i = 0; i < 4; i++)
    t[ty + i*8][tx] = src[(size_t)(r0 + ty + i*8)*C + c0 + tx];
  __syncthreads();
#pragma unroll
  for (int i = 0; i < 4; i++)
    dst[(size_t)(c0 + ty + i*8)*R + r0 + tx] = t[tx][ty + i*8];
}

extern "C" void kernel_launch(void* const* d_in, const int* in_sizes, int n_in,
                              void* d_out, int out_size, void* d_ws, size_t ws_size,
                              hipStream_t stream){
  const int B = 8, L = 2048, D = 1024, DK = 1024, DV = 1024;
  const float scale = 0.03125f;  // 1/sqrt(1024)

  const float* x  = (const float*)d_in[0];
  const int* alen = (const int*)d_in[1];
  const float* Wq = (const float*)d_in[2];
  const float* bq = (const float*)d_in[3];
  const float* Wk = (const float*)d_in[4];
  const float* bk = (const float*)d_in[5];
  const float* Wv = (const float*)d_in[6];
  const float* bv = (const float*)d_in[7];
  float* out = (float*)d_out;

  char* ws = (char*)d_ws;
  size_t off = 0;
  auto alloc = [&](size_t bytes) -> void* {
    void* p = ws + off;
    off += (bytes + 255) & ~(size_t)255;
    return p;
  };
  ushort* xb   = (ushort*)alloc((size_t)B*L*D*2);
  ushort* wqt  = (ushort*)alloc((size_t)DK*D*2);
  ushort* wkt  = (ushort*)alloc((size_t)DK*D*2);
  ushort* wvt  = (ushort*)alloc((size_t)DV*D*2);
  ushort* Qb   = (ushort*)alloc((size_t)B*L*DK*2);
  ushort* Kb   = (ushort*)alloc((size_t)B*L*DK*2);
  ushort* Vb   = (ushort*)alloc((size_t)B*L*DV*2);
  ushort* VTb  = (ushort*)alloc((size_t)B*DV*L*2);
  ushort* S    = (ushort*)alloc((size_t)B*L*L*2);
  float* partial = (float*)alloc((size_t)B*L*(L/64)*4);
  float* denom   = (float*)alloc((size_t)B*L*4);
  if (off > ws_size) return;   // workspace too small — bail cleanly

  dim3 tb(32, 8);

  // 1. x -> bf16
  long n4 = (long)B*L*D/4;
  cvt_f32_bf16<<<dim3((unsigned)((n4 + 255)/256)), 256, 0, stream>>>(x, xb, n4);

  // 2. W -> W^T bf16
  transpose_f32_bf16<<<dim3(DK/32, D/32), tb, 0, stream>>>(Wq, wqt, D, DK);
  transpose_f32_bf16<<<dim3(DK/32, D/32), tb, 0, stream>>>(Wk, wkt, D, DK);
  transpose_f32_bf16<<<dim3(DV/32, D/32), tb, 0, stream>>>(Wv, wvt, D, DV);

  // 3. projections: Q/K/V = x @ W + b   (M = B*L)
  gemm_bt<0><<<dim3(B*L/128, DK/128, 1), 256, 0, stream>>>(
      xb, wqt, bq, Qb, nullptr, B*L, DK, D, 0, 0, 0, 0.f, nullptr, nullptr);
  gemm_bt<0><<<dim3(B*L/128, DK/128, 1), 256, 0, stream>>>(
      xb, wkt, bk, Kb, nullptr, B*L, DK, D, 0, 0, 0, 0.f, nullptr, nullptr);
  gemm_bt<0><<<dim3(B*L/128, DV/128, 1), 256, 0, stream>>>(
      xb, wvt, bv, Vb, nullptr, B*L, DV, D, 0, 0, 0, 0.f, nullptr, nullptr);

  // 4. V -> V^T per batch
  transpose_bf16<<<dim3(DV/32, L/32, B), tb, 0, stream>>>(
      Vb, VTb, L, DV, (size_t)L*DV, (size_t)DV*L);

  // 5. scores: S = exp(scale * Q @ K^T), partial row sums (f32)
  gemm_bt<1><<<dim3(L/128, L/128, B), 256, 0, stream>>>(
      Qb, Kb, nullptr, S, nullptr, L, L, DK,
      (size_t)L*DK, (size_t)L*DK, (size_t)L*L, scale, partial, nullptr);

  // 6. denom = sum(partials) - (L - actulength)
  denom_k<<<dim3(B*L/256), 256, 0, stream>>>(partial, alen, denom, L, L/64);

  // 7. out = (S @ V) / denom
  gemm_bt<2><<<dim3(L/128, DV/128, B), 256, 0, stream>>>(
      S, VTb, nullptr, nullptr, out, L, DV, L,
      (size_t)L*L, (size_t)DV*L, (size_t)L*DV, 1.f, nullptr, denom);
}

// Round 2
// 365.389 us; speedup vs baseline: 1.2025x; 1.2025x over previous
//
#include <hip/hip_runtime.h>
#include <hip/hip_bf16.h>
#include <cstdint>

#define DEV __device__ __forceinline__

typedef __attribute__((ext_vector_type(8))) __bf16 bf16x8;
typedef __attribute__((ext_vector_type(4))) float f32x4;

DEV ushort f2bf(float f){
  uint32_t u = __builtin_bit_cast(uint32_t, f);
  u += 0x7fffu + ((u >> 16) & 1u);   // RNE
  return (ushort)(u >> 16);
}

DEV void gll16(const void* g, void* l){
  __builtin_amdgcn_global_load_lds((const __attribute__((address_space(1))) void*)g,
                                   (__attribute__((address_space(3))) void*)l, 16, 0, 0);
}

// ---------------------------------------------------------------------------
// 256x256 tile GEMM, C[M,N] = A[M,K] @ Bt[N,K]^T, bf16 in, f32 acc.
// 512 threads = 8 waves (2 M x 4 N), per-wave 128x64 output, BK=32.
// LDS: 4-slot ring per matrix, [128 LDS-rows][64 ushort] per slot (two logical
// rows per LDS row), XOR-swizzled so fragment ds_read_b128 is 2-way (free).
// Pipeline: counted vmcnt(8), 3 tiles prefetched ahead, 1 barrier per K-tile.
// MODE 0: C_bf16 = acc + bias[col]           (fused QKV projection)
// MODE 1: C_bf16 = exp(acc*scale), f32 partial row sums (scores)
// MODE 2: C_f32  = acc / denom[row]          (PV)
// ---------------------------------------------------------------------------
template<int MODE>
__global__ __launch_bounds__(512, 2) void gemm256(
    const ushort* __restrict__ A, const ushort* __restrict__ Bt,
    const float* __restrict__ bias,
    ushort* __restrict__ Cb, float* __restrict__ Cf,
    int gm, int gn, int K, int lda, int ldb, int ldc,
    size_t sA, size_t sB, size_t sC,
    float scale, float* __restrict__ partial, const float* __restrict__ denom,
    int Mrows, int nch)
{
  __shared__ __align__(16) ushort As[4][128][64];
  __shared__ __align__(16) ushort Bs[4][128][64];

  const int tid  = threadIdx.x;
  const int lane = tid & 63, wid = tid >> 6;
  const int wm = wid >> 2, wn = wid & 3;
  const int lr = lane & 15, fq = lane >> 4;
  const int lrh = lr >> 1;
  const int lo2 = ((lane & 1) << 2) | fq;

  // XCD-aware block swizzle (all grids are multiples of 8)
  const int nwg = gridDim.x;
  const int per = nwg >> 3;
  const int id  = blockIdx.x;
  const int swz = (id & 7) * per + (id >> 3);
  const int gmn = gm * gn;
  const int bz  = swz / gmn;
  const int rr  = swz - bz * gmn;
  const int bn  = rr / gm;
  const int bm  = rr - bn * gm;

  const ushort* Ab = A  + (size_t)bz * sA + (size_t)bm * 256 * (size_t)lda;
  const ushort* Bb = Bt + (size_t)bz * sB + (size_t)bn * 256 * (size_t)ldb;
  const int NT = K >> 5;   // K-tiles of 32 (K >= 96 guaranteed here)

  // stage tile t into ring slot s. chunk c (16B): LDS linear dest c*16.
  // content swizzle: LDS[R][ci] holds G[2R + (u>>2)][kchunk u&3], u = ci^(R&7).
  auto stageAB = [&](int t, int s){
    const size_t kb = (size_t)t * 64;   // byte offset along k (32 elem * 2B)
#pragma unroll
    for (int q = 0; q < 2; ++q){
      int c = q*512 + tid;
      int R = c >> 3, ci = c & 7;
      int u = ci ^ (R & 7);
      size_t sb = (size_t)(2*R + (u >> 2)) * (size_t)(lda*2) + kb + (size_t)((u & 3) << 4);
      gll16((const char*)Ab + sb,
            (ushort*)As + (size_t)s*8192 + (size_t)(q*512 + (wid << 6))*8);
    }
#pragma unroll
    for (int q = 0; q < 2; ++q){
      int c = q*512 + tid;
      int R = c >> 3, ci = c & 7;
      int u = ci ^ (R & 7);
      size_t sb = (size_t)(2*R + (u >> 2)) * (size_t)(ldb*2) + kb + (size_t)((u & 3) << 4);
      gll16((const char*)Bb + sb,
            (ushort*)Bs + (size_t)s*8192 + (size_t)(q*512 + (wid << 6))*8);
    }
  };

  f32x4 acc[8][4];
  const f32x4 z = {0.f, 0.f, 0.f, 0.f};
#pragma unroll
  for (int m = 0; m < 8; ++m)
#pragma unroll
    for (int n = 0; n < 4; ++n) acc[m][n] = z;

  // fragment ds_read offsets (ushort units). row = base + lr; R = row>>1;
  // R&7 == lrh always; swizzled chunk = lo2 ^ lrh (lane-constant).
  const int cio  = (lo2 ^ lrh) << 3;
  const int aoff = (wm*64 + lrh)*64 + cio;
  const int boff = (wn*32 + lrh)*64 + cio;

  // prologue: 3 tiles in flight
  stageAB(0, 0); stageAB(1, 1); stageAB(2, 2);

  for (int t = 0; t < NT; ++t){
    const int s = t & 3;
    // own ds_reads fully complete before crossing barrier (HW-level safety)
    asm volatile("s_waitcnt lgkmcnt(0)" ::: "memory");
    // tile t landed: everything older than the newest 8 loads (tiles t+1,t+2)
    asm volatile("s_waitcnt vmcnt(8)" ::: "memory");
    asm volatile("s_barrier" ::: "memory");
    if (t + 3 < NT) stageAB(t + 3, (t + 3) & 3);

    const ushort* Asl = (const ushort*)As + (size_t)s*8192;
    const ushort* Bsl = (const ushort*)Bs + (size_t)s*8192;
    bf16x8 af[8], bfv[4];
#pragma unroll
    for (int n = 0; n < 4; ++n)
      bfv[n] = *(const bf16x8*)&Bsl[boff + n*512];
#pragma unroll
    for (int m = 0; m < 8; ++m)
      af[m] = *(const bf16x8*)&Asl[aoff + m*512];
#pragma unroll
    for (int m = 0; m < 8; ++m)
#pragma unroll
      for (int n = 0; n < 4; ++n)
        acc[m][n] = __builtin_amdgcn_mfma_f32_16x16x32_bf16(af[m], bfv[n], acc[m][n], 0, 0, 0);
  }

  // ---------------- epilogue ----------------
  const int rbase = bm*256 + wm*128 + fq*4;
  const int cbase = bn*256 + wn*64 + lr;

  if (MODE == 0){
    ushort* dst = Cb + (size_t)bz * sC;
#pragma unroll
    for (int m = 0; m < 8; ++m){
      int r0 = rbase + m*16;
#pragma unroll
      for (int n = 0; n < 4; ++n){
        int c = cbase + n*16;
        float bvv = bias[c];
#pragma unroll
        for (int i = 0; i < 4; ++i)
          dst[(size_t)(r0 + i)*ldc + c] = f2bf(acc[m][n][i] + bvv);
      }
    }
  } else if (MODE == 1){
    ushort* dst = Cb + (size_t)bz * sC;
#pragma unroll
    for (int m = 0; m < 8; ++m){
      int r0 = rbase + m*16;
#pragma unroll
      for (int i = 0; i < 4; ++i){
        int r = r0 + i;
        float rs = 0.f;
#pragma unroll
        for (int n = 0; n < 4; ++n){
          float v = __expf(acc[m][n][i] * scale);
          dst[(size_t)r*ldc + cbase + n*16] = f2bf(v);
          rs += v;            // f32 sum from f32 exp values (NOT bf16-rounded)
        }
        rs += __shfl_xor(rs, 1);
        rs += __shfl_xor(rs, 2);
        rs += __shfl_xor(rs, 4);
        rs += __shfl_xor(rs, 8);
        if (lr == 0)
          partial[((size_t)bz*Mrows + r)*nch + (bn*4 + wn)] = rs;  // single writer
      }
    }
  } else {
    float* dst = Cf + (size_t)bz * sC;
#pragma unroll
    for (int m = 0; m < 8; ++m){
      int r0 = rbase + m*16;
#pragma unroll
      for (int i = 0; i < 4; ++i){
        int r = r0 + i;
        float inv = 1.0f / denom[(size_t)bz*Mrows + r];
#pragma unroll
        for (int n = 0; n < 4; ++n)
          dst[(size_t)r*ldc + cbase + n*16] = acc[m][n][i] * inv;
      }
    }
  }
}

// ---------------------------------------------------------------------------

__global__ void denom_k(const float* __restrict__ partial, const int* __restrict__ alen,
                        float* __restrict__ denom, int L, int nch){
  int i = blockIdx.x*blockDim.x + threadIdx.x;   // over B*L
  int b = i / L;
  const float* p = partial + (size_t)i*nch;
  float s = 0.f;
  for (int j = 0; j < nch; j++) s += p[j];
  denom[i] = s - (float)(L - alen[b]);
}

__global__ void cvt_f32_bf16(const float* __restrict__ in, ushort* __restrict__ out, long n4){
  long i = (long)blockIdx.x*blockDim.x + threadIdx.x;
  if (i >= n4) return;
  float4 f = ((const float4*)in)[i];
  ushort4 u;
  u.x = f2bf(f.x); u.y = f2bf(f.y); u.z = f2bf(f.z); u.w = f2bf(f.w);
  ((ushort4*)out)[i] = u;
}

// out[C,R] = in[R,C]^T with f32->bf16 convert. block (32,8)
__global__ __launch_bounds__(256) void transpose_f32_bf16(
    const float* __restrict__ in, ushort* __restrict__ out, int R, int C){
  __shared__ ushort t[32][33];
  int tx = threadIdx.x, ty = threadIdx.y;
  int c0 = blockIdx.x*32, r0 = blockIdx.y*32;
#pragma unroll
  for (int i = 0; i < 4; i++)
    t[ty + i*8][tx] = f2bf(in[(size_t)(r0 + ty + i*8)*C + c0 + tx]);
  __syncthreads();
#pragma unroll
  for (int i = 0; i < 4; i++)
    out[(size_t)(c0 + ty + i*8)*R + r0 + tx] = t[tx][ty + i*8];
}

// VT[b][c][r] = QKV[b*L + r][2048 + c]   (extract V and transpose, bf16)
__global__ __launch_bounds__(256) void transpose_v(
    const ushort* __restrict__ qkv, ushort* __restrict__ vt,
    int L_, int DV_, int ldq){
  __shared__ ushort tbuf[32][33];
  int bz = blockIdx.z;
  const ushort* src = qkv + (size_t)bz*L_*ldq + 2048;
  ushort* dst = vt + (size_t)bz*DV_*L_;
  int tx = threadIdx.x, ty = threadIdx.y;
  int c0 = blockIdx.x*32, r0 = blockIdx.y*32;
#pragma unroll
  for (int i = 0; i < 4; i++)
    tbuf[ty + i*8][tx] = src[(size_t)(r0 + ty + i*8)*ldq + c0 + tx];
  __syncthreads();
#pragma unroll
  for (int i = 0; i < 4; i++)
    dst[(size_t)(c0 + ty + i*8)*L_ + r0 + tx] = tbuf[tx][ty + i*8];
}

__global__ void pack_bias(const float* __restrict__ q, const float* __restrict__ k,
                          const float* __restrict__ v, float* __restrict__ o){
  int i = blockIdx.x*blockDim.x + threadIdx.x;   // 3072
  o[i] = (i < 1024) ? q[i] : (i < 2048 ? k[i-1024] : v[i-2048]);
}

// ---------------------------------------------------------------------------

extern "C" void kernel_launch(void* const* d_in, const int* in_sizes, int n_in,
                              void* d_out, int out_size, void* d_ws, size_t ws_size,
                              hipStream_t stream){
  const int B = 8, L = 2048, D = 1024, DK = 1024, DV = 1024;
  const float scale = 0.03125f;  // 1/sqrt(1024)

  const float* x  = (const float*)d_in[0];
  const int* alen = (const int*)d_in[1];
  const float* Wq = (const float*)d_in[2];
  const float* bq = (const float*)d_in[3];
  const float* Wk = (const float*)d_in[4];
  const float* bk = (const float*)d_in[5];
  const float* Wv = (const float*)d_in[6];
  const float* bv = (const float*)d_in[7];
  float* out = (float*)d_out;

  char* ws = (char*)d_ws;
  size_t off = 0;
  auto alloc = [&](size_t bytes) -> void* {
    void* p = ws + off;
    off += (bytes + 255) & ~(size_t)255;
    return p;
  };
  ushort* xb     = (ushort*)alloc((size_t)B*L*D*2);        // 32 MB (reused as VTb)
  ushort* wqkvT  = (ushort*)alloc((size_t)3*DK*D*2);       // 6 MB
  float*  bqkv   = (float*)alloc((size_t)3*DK*4);
  ushort* QKV    = (ushort*)alloc((size_t)B*L*3*DK*2);     // ~100 MB
  ushort* S      = (ushort*)alloc((size_t)B*L*L*2);        // 64 MB
  float* partial = (float*)alloc((size_t)B*L*32*4);        // 2 MB
  float* denom   = (float*)alloc((size_t)B*L*4);
  ushort* VTb    = xb;   // alias: xb dead after projection GEMM
  if (off > ws_size) return;

  dim3 tb(32, 8);

  // 1. x -> bf16
  long n4 = (long)B*L*D/4;
  cvt_f32_bf16<<<dim3((unsigned)((n4 + 255)/256)), 256, 0, stream>>>(x, xb, n4);

  // 2. packed W^T bf16 [3072][1024] + packed bias
  transpose_f32_bf16<<<dim3(DK/32, D/32), tb, 0, stream>>>(Wq, wqkvT,             D, DK);
  transpose_f32_bf16<<<dim3(DK/32, D/32), tb, 0, stream>>>(Wk, wqkvT + DK*D,      D, DK);
  transpose_f32_bf16<<<dim3(DV/32, D/32), tb, 0, stream>>>(Wv, wqkvT + 2*DK*D,    D, DV);
  pack_bias<<<dim3(12), 256, 0, stream>>>(bq, bk, bv, bqkv);

  // 3. fused QKV projection: QKV[B*L, 3072] = x @ [Wq|Wk|Wv] + b
  gemm256<0><<<dim3(64*12), 512, 0, stream>>>(
      xb, wqkvT, bqkv, QKV, nullptr, 64, 12, D, D, D, 3*DK,
      0, 0, 0, 0.f, nullptr, nullptr, 0, 0);

  // 4. V^T per batch (into xb's storage)
  transpose_v<<<dim3(DV/32, L/32, B), tb, 0, stream>>>(QKV, VTb, L, DV, 3*DK);

  // 5. scores: S = exp(scale * Q @ K^T), f32 partial row sums
  gemm256<1><<<dim3(8*8*8), 512, 0, stream>>>(
      QKV /*Q*/, QKV + DK /*K*/, nullptr, S, nullptr, 8, 8, DK, 3*DK, 3*DK, L,
      (size_t)L*3*DK, (size_t)L*3*DK, (size_t)L*L, scale, partial, nullptr, L, 32);

  // 6. denom = sum(partials) - (L - actulength)
  denom_k<<<dim3(B*L/256), 256, 0, stream>>>(partial, alen, denom, L, 32);

  // 7. out = (S @ V) / denom
  gemm256<2><<<dim3(8*4*8), 512, 0, stream>>>(
      S, VTb, nullptr, nullptr, out, 8, 4, L, L, L, DV,
      (size_t)L*L, (size_t)DV*L, (size_t)L*DV, 1.f, nullptr, denom, L, 0);
}

// Round 3
// 317.932 us; speedup vs baseline: 1.3820x; 1.1493x over previous
//
#include <hip/hip_runtime.h>
#include <hip/hip_bf16.h>
#include <cstdint>

#define DEV __device__ __forceinline__

typedef __attribute__((ext_vector_type(8))) __bf16 bf16x8;
typedef __attribute__((ext_vector_type(4))) float f32x4;

DEV ushort f2bf(float f){
  uint32_t u = __builtin_bit_cast(uint32_t, f);
  u += 0x7fffu + ((u >> 16) & 1u);   // RNE
  return (ushort)(u >> 16);
}

DEV void gll16(const void* g, void* l){
  __builtin_amdgcn_global_load_lds((const __attribute__((address_space(1))) void*)g,
                                   (__attribute__((address_space(3))) void*)l, 16, 0, 0);
}

// ---------------------------------------------------------------------------
// 256x256 tile GEMM, C[M,N] = A[M,K] @ Bt[N,K]^T, bf16 in, f32 acc.
// 512 threads = 8 waves (2 M x 4 N), per-wave 128x64 output, K-slot = 32.
// LDS: 4-slot ring per matrix (128 KiB total), XOR-swizzled (2-way = free).
// Schedule: 2 lockstep phases per slot (= m201's 8-phase grain per 128 K):
//   P0: ds_read B(4)+A_mh0(4); stage A(t+2); bar; lgkm0; prio1; 16 MFMA; prio0; bar
//   P1: ds_read A_mh1(4);      stage B(t+2); bar; lgkm0; prio1; 16 MFMA; prio0
//   slot tail: counted vmcnt(4) (slot t+1 landed, t+2 in flight); bar
// MODE 0: C_bf16 = acc + bias[col]           (fused QKV projection)
// MODE 1: C_bf16 = exp(acc*scale), f32 partial row sums (scores)
// MODE 2: C_f32  = acc / denom[row]          (PV)
// ---------------------------------------------------------------------------
template<int MODE>
__global__ __launch_bounds__(512, 2) void gemm256(
    const ushort* __restrict__ A, const ushort* __restrict__ Bt,
    const float* __restrict__ bias,
    ushort* __restrict__ Cb, float* __restrict__ Cf,
    int gm, int gn, int K, int lda, int ldb, int ldc,
    size_t sA, size_t sB, size_t sC,
    float scale, float* __restrict__ partial, const float* __restrict__ denom,
    int Mrows, int nch)
{
  __shared__ __align__(16) ushort As[4][128][64];
  __shared__ __align__(16) ushort Bs[4][128][64];

  const int tid  = threadIdx.x;
  const int lane = tid & 63, wid = tid >> 6;
  const int wm = wid >> 2, wn = wid & 3;
  const int lr = lane & 15, fq = lane >> 4;
  const int lrh = lr >> 1;
  const int lo2 = ((lane & 1) << 2) | fq;

  // XCD-aware block swizzle (all grids are multiples of 8)
  const int nwg = gridDim.x;
  const int per = nwg >> 3;
  const int id  = blockIdx.x;
  const int swz = (id & 7) * per + (id >> 3);
  const int gmn = gm * gn;
  const int bz  = swz / gmn;
  const int rr  = swz - bz * gmn;
  const int bn  = rr / gm;
  const int bm  = rr - bn * gm;

  const ushort* Ab = A  + (size_t)bz * sA + (size_t)bm * 256 * (size_t)lda;
  const ushort* Bb = Bt + (size_t)bz * sB + (size_t)bn * 256 * (size_t)ldb;
  const int NT = K >> 5;   // K-slots of 32 (K >= 128 everywhere here)

  // stage slot t's A (or B) half: 2 x gll16 per thread, 16 KB = 256 rows x 32 k.
  // content swizzle: LDS[R][ci] holds G[2R + (u>>2)][kchunk u&3], u = ci^(R&7).
  auto stageA = [&](int t){
    const int s = t & 3;
    const size_t kb = (size_t)t * 64;   // byte offset along k
#pragma unroll
    for (int q = 0; q < 2; ++q){
      int c = q*512 + tid;
      int R = c >> 3, ci = c & 7;
      int u = ci ^ (R & 7);
      size_t sb = (size_t)(2*R + (u >> 2)) * (size_t)(lda*2) + kb + (size_t)((u & 3) << 4);
      gll16((const char*)Ab + sb,
            (ushort*)As + (size_t)s*8192 + (size_t)(q*512 + (wid << 6))*8);
    }
  };
  auto stageB = [&](int t){
    const int s = t & 3;
    const size_t kb = (size_t)t * 64;
#pragma unroll
    for (int q = 0; q < 2; ++q){
      int c = q*512 + tid;
      int R = c >> 3, ci = c & 7;
      int u = ci ^ (R & 7);
      size_t sb = (size_t)(2*R + (u >> 2)) * (size_t)(ldb*2) + kb + (size_t)((u & 3) << 4);
      gll16((const char*)Bb + sb,
            (ushort*)Bs + (size_t)s*8192 + (size_t)(q*512 + (wid << 6))*8);
    }
  };

  f32x4 acc[8][4];
  const f32x4 z = {0.f, 0.f, 0.f, 0.f};
#pragma unroll
  for (int m = 0; m < 8; ++m)
#pragma unroll
    for (int n = 0; n < 4; ++n) acc[m][n] = z;

  // fragment ds_read offsets (ushort units). row = base + lr; R = row>>1;
  // R&7 == lrh always; swizzled chunk = lo2 ^ lrh (lane-constant).
  const int cio  = (lo2 ^ lrh) << 3;
  const int aoff = (wm*64 + lrh)*64 + cio;
  const int boff = (wn*32 + lrh)*64 + cio;

  // prologue: slots 0 and 1 in flight (8 loads/thread)
  stageA(0); stageB(0); stageA(1); stageB(1);
  asm volatile("s_waitcnt vmcnt(4)" ::: "memory");   // slot 0 landed (mine)
  __builtin_amdgcn_s_barrier();                      // -> slot 0 landed (all waves)

  for (int t = 0; t < NT; ++t){
    const int s = t & 3;
    const ushort* Asl = (const ushort*)As + (size_t)s*8192;
    const ushort* Bsl = (const ushort*)Bs + (size_t)s*8192;
    const bool pre = (t + 2 < NT);

    // ---- phase 0: B-frags + A-frags mh0, MFMA quadrant mh0 ----
    bf16x8 bfv[4], af0[4];
#pragma unroll
    for (int n = 0; n < 4; ++n)
      bfv[n] = *(const bf16x8*)&Bsl[boff + n*512];
#pragma unroll
    for (int m = 0; m < 4; ++m)
      af0[m] = *(const bf16x8*)&Asl[aoff + m*512];
    if (pre) stageA(t + 2);
    __builtin_amdgcn_s_barrier();
    asm volatile("s_waitcnt lgkmcnt(0)" ::: "memory");
    __builtin_amdgcn_sched_barrier(0);
    __builtin_amdgcn_s_setprio(1);
#pragma unroll
    for (int m = 0; m < 4; ++m)
#pragma unroll
      for (int n = 0; n < 4; ++n)
        acc[m][n] = __builtin_amdgcn_mfma_f32_16x16x32_bf16(af0[m], bfv[n], acc[m][n], 0, 0, 0);
    __builtin_amdgcn_s_setprio(0);
    __builtin_amdgcn_s_barrier();

    // ---- phase 1: A-frags mh1, MFMA quadrant mh1 ----
    bf16x8 af1[4];
#pragma unroll
    for (int m = 0; m < 4; ++m)
      af1[m] = *(const bf16x8*)&Asl[aoff + (m + 4)*512];
    if (pre) stageB(t + 2);
    __builtin_amdgcn_s_barrier();
    asm volatile("s_waitcnt lgkmcnt(0)" ::: "memory");
    __builtin_amdgcn_sched_barrier(0);
    __builtin_amdgcn_s_setprio(1);
#pragma unroll
    for (int m = 0; m < 4; ++m)
#pragma unroll
      for (int n = 0; n < 4; ++n)
        acc[m + 4][n] = __builtin_amdgcn_mfma_f32_16x16x32_bf16(af1[m], bfv[n], acc[m + 4][n], 0, 0, 0);
    __builtin_amdgcn_s_setprio(0);

    // ---- slot tail: guarantee slot t+1 landed (counted — never 0 mid-loop) ----
    if (t < NT - 1){
      if (t + 2 < NT) asm volatile("s_waitcnt vmcnt(4)" ::: "memory");
      else            asm volatile("s_waitcnt vmcnt(0)" ::: "memory");
      __builtin_amdgcn_s_barrier();
    }
  }

  // ---------------- epilogue ----------------
  const int rbase = bm*256 + wm*128 + fq*4;
  const int cbase = bn*256 + wn*64 + lr;

  if (MODE == 0){
    ushort* dst = Cb + (size_t)bz * sC;
#pragma unroll
    for (int m = 0; m < 8; ++m){
      int r0 = rbase + m*16;
#pragma unroll
      for (int n = 0; n < 4; ++n){
        int c = cbase + n*16;
        float bvv = bias[c];
#pragma unroll
        for (int i = 0; i < 4; ++i)
          dst[(size_t)(r0 + i)*ldc + c] = f2bf(acc[m][n][i] + bvv);
      }
    }
  } else if (MODE == 1){
    ushort* dst = Cb + (size_t)bz * sC;
#pragma unroll
    for (int m = 0; m < 8; ++m){
      int r0 = rbase + m*16;
#pragma unroll
      for (int i = 0; i < 4; ++i){
        int r = r0 + i;
        float rs = 0.f;
#pragma unroll
        for (int n = 0; n < 4; ++n){
          float v = __expf(acc[m][n][i] * scale);
          dst[(size_t)r*ldc + cbase + n*16] = f2bf(v);
          rs += v;            // f32 sum from f32 exp values (NOT bf16-rounded)
        }
        rs += __shfl_xor(rs, 1);
        rs += __shfl_xor(rs, 2);
        rs += __shfl_xor(rs, 4);
        rs += __shfl_xor(rs, 8);
        if (lr == 0)
          partial[((size_t)bz*Mrows + r)*nch + (bn*4 + wn)] = rs;  // single writer
      }
    }
  } else {
    float* dst = Cf + (size_t)bz * sC;
#pragma unroll
    for (int m = 0; m < 8; ++m){
      int r0 = rbase + m*16;
#pragma unroll
      for (int i = 0; i < 4; ++i){
        int r = r0 + i;
        float inv = 1.0f / denom[(size_t)bz*Mrows + r];
#pragma unroll
        for (int n = 0; n < 4; ++n)
          dst[(size_t)r*ldc + cbase + n*16] = acc[m][n][i] * inv;
      }
    }
  }
}

// ---------------------------------------------------------------------------

__global__ void denom_k(const float* __restrict__ partial, const int* __restrict__ alen,
                        float* __restrict__ denom, int L, int nch){
  int i = blockIdx.x*blockDim.x + threadIdx.x;   // over B*L
  int b = i / L;
  const float* p = partial + (size_t)i*nch;
  float s = 0.f;
  for (int j = 0; j < nch; j++) s += p[j];
  denom[i] = s - (float)(L - alen[b]);
}

__global__ void cvt_f32_bf16(const float* __restrict__ in, ushort* __restrict__ out, long n4){
  long i = (long)blockIdx.x*blockDim.x + threadIdx.x;
  if (i >= n4) return;
  float4 f = ((const float4*)in)[i];
  ushort4 u;
  u.x = f2bf(f.x); u.y = f2bf(f.y); u.z = f2bf(f.z); u.w = f2bf(f.w);
  ((ushort4*)out)[i] = u;
}

// out[C,R] = in[R,C]^T with f32->bf16 convert. block (32,8)
__global__ __launch_bounds__(256) void transpose_f32_bf16(
    const float* __restrict__ in, ushort* __restrict__ out, int R, int C){
  __shared__ ushort t[32][33];
  int tx = threadIdx.x, ty = threadIdx.y;
  int c0 = blockIdx.x*32, r0 = blockIdx.y*32;
#pragma unroll
  for (int i = 0; i < 4; i++)
    t[ty + i*8][tx] = f2bf(in[(size_t)(r0 + ty + i*8)*C + c0 + tx]);
  __syncthreads();
#pragma unroll
  for (int i = 0; i < 4; i++)
    out[(size_t)(c0 + ty + i*8)*R + r0 + tx] = t[tx][ty + i*8];
}

// VT[b][c][r] = QKV[b*L + r][2048 + c]   (extract V and transpose, bf16)
__global__ __launch_bounds__(256) void transpose_v(
    const ushort* __restrict__ qkv, ushort* __restrict__ vt,
    int L_, int DV_, int ldq){
  __shared__ ushort tbuf[32][33];
  int bz = blockIdx.z;
  const ushort* src = qkv + (size_t)bz*L_*ldq + 2048;
  ushort* dst = vt + (size_t)bz*DV_*L_;
  int tx = threadIdx.x, ty = threadIdx.y;
  int c0 = blockIdx.x*32, r0 = blockIdx.y*32;
#pragma unroll
  for (int i = 0; i < 4; i++)
    tbuf[ty + i*8][tx] = src[(size_t)(r0 + ty + i*8)*ldq + c0 + tx];
  __syncthreads();
#pragma unroll
  for (int i = 0; i < 4; i++)
    dst[(size_t)(c0 + ty + i*8)*L_ + r0 + tx] = tbuf[tx][ty + i*8];
}

__global__ void pack_bias(const float* __restrict__ q, const float* __restrict__ k,
                          const float* __restrict__ v, float* __restrict__ o){
  int i = blockIdx.x*blockDim.x + threadIdx.x;   // 3072
  o[i] = (i < 1024) ? q[i] : (i < 2048 ? k[i-1024] : v[i-2048]);
}

// ---------------------------------------------------------------------------

extern "C" void kernel_launch(void* const* d_in, const int* in_sizes, int n_in,
                              void* d_out, int out_size, void* d_ws, size_t ws_size,
                              hipStream_t stream){
  const int B = 8, L = 2048, D = 1024, DK = 1024, DV = 1024;
  const float scale = 0.03125f;  // 1/sqrt(1024)

  const float* x  = (const float*)d_in[0];
  const int* alen = (const int*)d_in[1];
  const float* Wq = (const float*)d_in[2];
  const float* bq = (const float*)d_in[3];
  const float* Wk = (const float*)d_in[4];
  const float* bk = (const float*)d_in[5];
  const float* Wv = (const float*)d_in[6];
  const float* bv = (const float*)d_in[7];
  float* out = (float*)d_out;

  char* ws = (char*)d_ws;
  size_t off = 0;
  auto alloc = [&](size_t bytes) -> void* {
    void* p = ws + off;
    off += (bytes + 255) & ~(size_t)255;
    return p;
  };
  ushort* xb     = (ushort*)alloc((size_t)B*L*D*2);        // 32 MB (reused as VTb)
  ushort* wqkvT  = (ushort*)alloc((size_t)3*DK*D*2);       // 6 MB
  float*  bqkv   = (float*)alloc((size_t)3*DK*4);
  ushort* QKV    = (ushort*)alloc((size_t)B*L*3*DK*2);     // ~100 MB
  ushort* S      = (ushort*)alloc((size_t)B*L*L*2);        // 64 MB
  float* partial = (float*)alloc((size_t)B*L*32*4);        // 2 MB
  float* denom   = (float*)alloc((size_t)B*L*4);
  ushort* VTb    = xb;   // alias: xb dead after projection GEMM
  if (off > ws_size) return;

  dim3 tb(32, 8);

  // 1. x -> bf16
  long n4 = (long)B*L*D/4;
  cvt_f32_bf16<<<dim3((unsigned)((n4 + 255)/256)), 256, 0, stream>>>(x, xb, n4);

  // 2. packed W^T bf16 [3072][1024] + packed bias
  transpose_f32_bf16<<<dim3(DK/32, D/32), tb, 0, stream>>>(Wq, wqkvT,             D, DK);
  transpose_f32_bf16<<<dim3(DK/32, D/32), tb, 0, stream>>>(Wk, wqkvT + DK*D,      D, DK);
  transpose_f32_bf16<<<dim3(DV/32, D/32), tb, 0, stream>>>(Wv, wqkvT + 2*DK*D,    D, DV);
  pack_bias<<<dim3(12), 256, 0, stream>>>(bq, bk, bv, bqkv);

  // 3. fused QKV projection: QKV[B*L, 3072] = x @ [Wq|Wk|Wv] + b
  gemm256<0><<<dim3(64*12), 512, 0, stream>>>(
      xb, wqkvT, bqkv, QKV, nullptr, 64, 12, D, D, D, 3*DK,
      0, 0, 0, 0.f, nullptr, nullptr, 0, 0);

  // 4. V^T per batch (into xb's storage)
  transpose_v<<<dim3(DV/32, L/32, B), tb, 0, stream>>>(QKV, VTb, L, DV, 3*DK);

  // 5. scores: S = exp(scale * Q @ K^T), f32 partial row sums
  gemm256<1><<<dim3(8*8*8), 512, 0, stream>>>(
      QKV /*Q*/, QKV + DK /*K*/, nullptr, S, nullptr, 8, 8, DK, 3*DK, 3*DK, L,
      (size_t)L*3*DK, (size_t)L*3*DK, (size_t)L*L, scale, partial, nullptr, L, 32);

  // 6. denom = sum(partials) - (L - actulength)
  denom_k<<<dim3(B*L/256), 256, 0, stream>>>(partial, alen, denom, L, 32);

  // 7. out = (S @ V) / denom
  gemm256<2><<<dim3(8*4*8), 512, 0, stream>>>(
      S, VTb, nullptr, nullptr, out, 8, 4, L, L, L, DV,
      (size_t)L*L, (size_t)DV*L, (size_t)L*DV, 1.f, nullptr, denom, L, 0);
}

// Round 4
// 311.314 us; speedup vs baseline: 1.4114x; 1.0213x over previous
//
#include <hip/hip_runtime.h>
#include <hip/hip_bf16.h>
#include <cstdint>

#define DEV __device__ __forceinline__

typedef __attribute__((ext_vector_type(8))) __bf16 bf16x8;
typedef __attribute__((ext_vector_type(4))) float f32x4;

DEV ushort f2bf(float f){
  uint32_t u = __builtin_bit_cast(uint32_t, f);
  u += 0x7fffu + ((u >> 16) & 1u);   // RNE
  return (ushort)(u >> 16);
}

DEV void gll16(const void* g, void* l){
  __builtin_amdgcn_global_load_lds((const __attribute__((address_space(1))) void*)g,
                                   (__attribute__((address_space(3))) void*)l, 16, 0, 0);
}

// ---------------------------------------------------------------------------
// 256x256 tile GEMM, C[M,N] = A[M,K] @ Bt[N,K]^T, bf16 in, f32 acc.
// 512 threads = 8 waves (2 M x 4 N), per-wave 128x64 output, K-slot = 32.
// LDS: 4-slot ring per matrix (128 KiB), XOR-swizzled (2-way = free, 0 confl).
// Schedule: 2 lockstep phases per slot; prefetch depth = 3 slots (ring full);
// tail vmcnt(8) -> waited loads were issued ~2.5 slots ago (latency hiding).
// MODE 0: C_bf16 = acc + bias[col]; bn>=8 writes V transposed to VTout
// MODE 1: C_bf16 = exp(acc*scale), f32 partial row sums (scores)
// MODE 2: C_f32  = acc / denom[row]          (PV)
// ---------------------------------------------------------------------------
template<int MODE>
__global__ __launch_bounds__(512, 2) void gemm256(
    const ushort* __restrict__ A, const ushort* __restrict__ Bt,
    const float* __restrict__ bias,
    ushort* __restrict__ Cb, float* __restrict__ Cf, ushort* __restrict__ VTout,
    int gm, int gn, int K, int lda, int ldb, int ldc,
    size_t sA, size_t sB, size_t sC,
    float scale, float* __restrict__ partial, const float* __restrict__ denom,
    int Mrows, int nch)
{
  __shared__ __align__(16) ushort As[4][128][64];
  __shared__ __align__(16) ushort Bs[4][128][64];

  const int tid  = threadIdx.x;
  const int lane = tid & 63, wid = tid >> 6;
  const int wm = wid >> 2, wn = wid & 3;
  const int lr = lane & 15, fq = lane >> 4;
  const int lrh = lr >> 1;
  const int lo2 = ((lane & 1) << 2) | fq;

  // XCD-aware block swizzle (all grids are multiples of 8)
  const int nwg = gridDim.x;
  const int per = nwg >> 3;
  const int id  = blockIdx.x;
  const int swz = (id & 7) * per + (id >> 3);
  const int gmn = gm * gn;
  const int bz  = swz / gmn;
  const int rr  = swz - bz * gmn;
  const int bn  = rr / gm;
  const int bm  = rr - bn * gm;

  const ushort* Ab = A  + (size_t)bz * sA + (size_t)bm * 256 * (size_t)lda;
  const ushort* Bb = Bt + (size_t)bz * sB + (size_t)bn * 256 * (size_t)ldb;
  const int NT = K >> 5;   // K-slots of 32 (NT >= 32 for every call here)

  // ---- hoisted stage addressing ----
  // chunk c (16B): LDS linear dest c*16 within slot.
  // content swizzle: LDS[R][ci] holds G[2R + (u>>2)][kchunk u&3], u = ci^(R&7).
  auto srcOff = [&](int c, int ld)->size_t{
    int R = c >> 3, ci = c & 7, u = ci ^ (R & 7);
    return (size_t)(2*R + (u >> 2)) * (size_t)(ld*2) + (size_t)((u & 3) << 4);
  };
  const char* srcA0 = (const char*)Ab + srcOff(tid,       lda);
  const char* srcA1 = (const char*)Ab + srcOff(512 + tid, lda);
  const char* srcB0 = (const char*)Bb + srcOff(tid,       ldb);
  const char* srcB1 = (const char*)Bb + srcOff(512 + tid, ldb);
  char* AsB = (char*)As;
  char* BsB = (char*)Bs;
  const int dst0 = (wid << 6) * 16;          // wave-uniform; HW adds lane*16
  const int dst1 = (512 + (wid << 6)) * 16;

  auto stageA = [&](int t){
    const int sb = (t & 3) << 14;            // slot * 16384 B
    const size_t kb = (size_t)t << 6;        // t * 64 B along k
    gll16(srcA0 + kb, AsB + sb + dst0);
    gll16(srcA1 + kb, AsB + sb + dst1);
  };
  auto stageB = [&](int t){
    const int sb = (t & 3) << 14;
    const size_t kb = (size_t)t << 6;
    gll16(srcB0 + kb, BsB + sb + dst0);
    gll16(srcB1 + kb, BsB + sb + dst1);
  };

  f32x4 acc[8][4];
  const f32x4 z = {0.f, 0.f, 0.f, 0.f};
#pragma unroll
  for (int m = 0; m < 8; ++m)
#pragma unroll
    for (int n = 0; n < 4; ++n) acc[m][n] = z;

  // fragment ds_read offsets (ushort units); swizzled chunk lane-constant.
  const int cio  = (lo2 ^ lrh) << 3;
  const int aoff = (wm*64 + lrh)*64 + cio;
  const int boff = (wn*32 + lrh)*64 + cio;

  // prologue: slots 0,1,2 in flight (12 loads/thread)
  stageA(0); stageB(0); stageA(1); stageB(1); stageA(2); stageB(2);
  asm volatile("s_waitcnt vmcnt(8)" ::: "memory");   // slot 0 landed (mine)
  __builtin_amdgcn_s_barrier();                      // slot 0 landed (all)

  for (int t = 0; t < NT; ++t){
    const int s = t & 3;
    const ushort* Asl = (const ushort*)As + (size_t)s*8192;
    const ushort* Bsl = (const ushort*)Bs + (size_t)s*8192;
    const bool pre = (t + 3 < NT);

    // ---- phase 0: B-frags + A-frags m0-3, MFMA half m0-3 ----
    bf16x8 bfv[4], af0[4];
#pragma unroll
    for (int n = 0; n < 4; ++n)
      bfv[n] = *(const bf16x8*)&Bsl[boff + n*512];
#pragma unroll
    for (int m = 0; m < 4; ++m)
      af0[m] = *(const bf16x8*)&Asl[aoff + m*512];
    if (pre) stageA(t + 3);
    __builtin_amdgcn_s_barrier();
    asm volatile("s_waitcnt lgkmcnt(0)" ::: "memory");
    __builtin_amdgcn_sched_barrier(0);
    __builtin_amdgcn_s_setprio(1);
#pragma unroll
    for (int m = 0; m < 4; ++m)
#pragma unroll
      for (int n = 0; n < 4; ++n)
        acc[m][n] = __builtin_amdgcn_mfma_f32_16x16x32_bf16(af0[m], bfv[n], acc[m][n], 0, 0, 0);
    __builtin_amdgcn_s_setprio(0);
    __builtin_amdgcn_s_barrier();

    // ---- phase 1: A-frags m4-7, MFMA half m4-7 (B-frags reused) ----
    bf16x8 af1[4];
#pragma unroll
    for (int m = 0; m < 4; ++m)
      af1[m] = *(const bf16x8*)&Asl[aoff + (m + 4)*512];
    if (pre) stageB(t + 3);
    __builtin_amdgcn_s_barrier();
    asm volatile("s_waitcnt lgkmcnt(0)" ::: "memory");
    __builtin_amdgcn_sched_barrier(0);
    __builtin_amdgcn_s_setprio(1);
#pragma unroll
    for (int m = 0; m < 4; ++m)
#pragma unroll
      for (int n = 0; n < 4; ++n)
        acc[m + 4][n] = __builtin_amdgcn_mfma_f32_16x16x32_bf16(af1[m], bfv[n], acc[m + 4][n], 0, 0, 0);
    __builtin_amdgcn_s_setprio(0);

    // ---- slot tail: guarantee slot t+1 landed (counted; drains only at end) ----
    if (t < NT - 1){
      if      (t + 3 < NT) asm volatile("s_waitcnt vmcnt(8)" ::: "memory");
      else if (t + 2 < NT) asm volatile("s_waitcnt vmcnt(4)" ::: "memory");
      else                 asm volatile("s_waitcnt vmcnt(0)" ::: "memory");
      __builtin_amdgcn_s_barrier();
    }
  }

  // ---------------- epilogue ----------------
  const int rbase = bm*256 + wm*128 + fq*4;
  const int cbase = bn*256 + wn*64 + lr;

  if (MODE == 0){
    if (bn >= 8){
      // V block: write transposed, VT[b][dv][l], contiguous ushort4 over l
#pragma unroll
      for (int m = 0; m < 8; ++m){
        int r0 = rbase + m*16;
        int b = r0 >> 11, l = r0 & 2047;
        ushort* vb = VTout + (size_t)b * 1024 * 2048;
#pragma unroll
        for (int n = 0; n < 4; ++n){
          int c = cbase + n*16;
          float bvv = bias[c];
          ushort4 u4;
          u4.x = f2bf(acc[m][n][0] + bvv);
          u4.y = f2bf(acc[m][n][1] + bvv);
          u4.z = f2bf(acc[m][n][2] + bvv);
          u4.w = f2bf(acc[m][n][3] + bvv);
          *(ushort4*)&vb[(size_t)(c - 2048)*2048 + l] = u4;
        }
      }
    } else {
      ushort* dst = Cb + (size_t)bz * sC;
#pragma unroll
      for (int m = 0; m < 8; ++m){
        int r0 = rbase + m*16;
#pragma unroll
        for (int n = 0; n < 4; ++n){
          int c = cbase + n*16;
          float bvv = bias[c];
#pragma unroll
          for (int i = 0; i < 4; ++i)
            dst[(size_t)(r0 + i)*ldc + c] = f2bf(acc[m][n][i] + bvv);
        }
      }
    }
  } else if (MODE == 1){
    ushort* dst = Cb + (size_t)bz * sC;
#pragma unroll
    for (int m = 0; m < 8; ++m){
      int r0 = rbase + m*16;
#pragma unroll
      for (int i = 0; i < 4; ++i){
        int r = r0 + i;
        float rs = 0.f;
#pragma unroll
        for (int n = 0; n < 4; ++n){
          float v = __expf(acc[m][n][i] * scale);
          dst[(size_t)r*ldc + cbase + n*16] = f2bf(v);
          rs += v;            // f32 sum from f32 exp values (NOT bf16-rounded)
        }
        rs += __shfl_xor(rs, 1);
        rs += __shfl_xor(rs, 2);
        rs += __shfl_xor(rs, 4);
        rs += __shfl_xor(rs, 8);
        if (lr == 0)
          partial[((size_t)bz*Mrows + r)*nch + (bn*4 + wn)] = rs;  // single writer
      }
    }
  } else {
    float* dst = Cf + (size_t)bz * sC;
#pragma unroll
    for (int m = 0; m < 8; ++m){
      int r0 = rbase + m*16;
#pragma unroll
      for (int i = 0; i < 4; ++i){
        int r = r0 + i;
        float inv = 1.0f / denom[(size_t)bz*Mrows + r];
#pragma unroll
        for (int n = 0; n < 4; ++n)
          dst[(size_t)r*ldc + cbase + n*16] = acc[m][n][i] * inv;
      }
    }
  }
}

// ---------------------------------------------------------------------------

__global__ void denom_k(const float* __restrict__ partial, const int* __restrict__ alen,
                        float* __restrict__ denom, int L, int nch){
  int i = blockIdx.x*blockDim.x + threadIdx.x;   // over B*L
  int b = i / L;
  const float* p = partial + (size_t)i*nch;
  float s = 0.f;
  for (int j = 0; j < nch; j++) s += p[j];
  denom[i] = s - (float)(L - alen[b]);
}

__global__ void cvt_f32_bf16(const float* __restrict__ in, ushort* __restrict__ out, long n4){
  long i = (long)blockIdx.x*blockDim.x + threadIdx.x;
  if (i >= n4) return;
  float4 f = ((const float4*)in)[i];
  ushort4 u;
  u.x = f2bf(f.x); u.y = f2bf(f.y); u.z = f2bf(f.z); u.w = f2bf(f.w);
  ((ushort4*)out)[i] = u;
}

// out[C,R] = in[R,C]^T with f32->bf16 convert. block (32,8)
__global__ __launch_bounds__(256) void transpose_f32_bf16(
    const float* __restrict__ in, ushort* __restrict__ out, int R, int C){
  __shared__ ushort t[32][33];
  int tx = threadIdx.x, ty = threadIdx.y;
  int c0 = blockIdx.x*32, r0 = blockIdx.y*32;
#pragma unroll
  for (int i = 0; i < 4; i++)
    t[ty + i*8][tx] = f2bf(in[(size_t)(r0 + ty + i*8)*C + c0 + tx]);
  __syncthreads();
#pragma unroll
  for (int i = 0; i < 4; i++)
    out[(size_t)(c0 + ty + i*8)*R + r0 + tx] = t[tx][ty + i*8];
}

__global__ void pack_bias(const float* __restrict__ q, const float* __restrict__ k,
                          const float* __restrict__ v, float* __restrict__ o){
  int i = blockIdx.x*blockDim.x + threadIdx.x;   // 3072
  o[i] = (i < 1024) ? q[i] : (i < 2048 ? k[i-1024] : v[i-2048]);
}

// ---------------------------------------------------------------------------

extern "C" void kernel_launch(void* const* d_in, const int* in_sizes, int n_in,
                              void* d_out, int out_size, void* d_ws, size_t ws_size,
                              hipStream_t stream){
  const int B = 8, L = 2048, D = 1024, DK = 1024, DV = 1024;
  const float scale = 0.03125f;  // 1/sqrt(1024)

  const float* x  = (const float*)d_in[0];
  const int* alen = (const int*)d_in[1];
  const float* Wq = (const float*)d_in[2];
  const float* bq = (const float*)d_in[3];
  const float* Wk = (const float*)d_in[4];
  const float* bk = (const float*)d_in[5];
  const float* Wv = (const float*)d_in[6];
  const float* bv = (const float*)d_in[7];
  float* out = (float*)d_out;

  char* ws = (char*)d_ws;
  size_t off = 0;
  auto alloc = [&](size_t bytes) -> void* {
    void* p = ws + off;
    off += (bytes + 255) & ~(size_t)255;
    return p;
  };
  ushort* xb     = (ushort*)alloc((size_t)B*L*D*2);        // 32 MB
  ushort* wqkvT  = (ushort*)alloc((size_t)3*DK*D*2);       // 6 MB
  float*  bqkv   = (float*)alloc((size_t)3*DK*4);
  ushort* QK     = (ushort*)alloc((size_t)B*L*2*DK*2);     // 67 MB (Q|K packed rows)
  ushort* VTb    = (ushort*)alloc((size_t)B*DV*L*2);       // 32 MB (V transposed)
  ushort* S      = (ushort*)alloc((size_t)B*L*L*2);        // 64 MB
  float* partial = (float*)alloc((size_t)B*L*32*4);        // 2 MB
  float* denom   = (float*)alloc((size_t)B*L*4);
  if (off > ws_size) return;

  dim3 tb(32, 8);

  // 1. x -> bf16
  long n4 = (long)B*L*D/4;
  cvt_f32_bf16<<<dim3((unsigned)((n4 + 255)/256)), 256, 0, stream>>>(x, xb, n4);

  // 2. packed W^T bf16 [3072][1024] + packed bias
  transpose_f32_bf16<<<dim3(DK/32, D/32), tb, 0, stream>>>(Wq, wqkvT,          D, DK);
  transpose_f32_bf16<<<dim3(DK/32, D/32), tb, 0, stream>>>(Wk, wqkvT + DK*D,   D, DK);
  transpose_f32_bf16<<<dim3(DV/32, D/32), tb, 0, stream>>>(Wv, wqkvT + 2*DK*D, D, DV);
  pack_bias<<<dim3(12), 256, 0, stream>>>(bq, bk, bv, bqkv);

  // 3. fused QKV projection: Q,K -> QK[B*L, 2048]; V -> VTb transposed
  gemm256<0><<<dim3(64*12), 512, 0, stream>>>(
      xb, wqkvT, bqkv, QK, nullptr, VTb, 64, 12, D, D, D, 2*DK,
      0, 0, 0, 0.f, nullptr, nullptr, 0, 0);

  // 4. scores: S = exp(scale * Q @ K^T), f32 partial row sums
  gemm256<1><<<dim3(8*8*8), 512, 0, stream>>>(
      QK /*Q*/, QK + DK /*K*/, nullptr, S, nullptr, nullptr, 8, 8, DK,
      2*DK, 2*DK, L,
      (size_t)L*2*DK, (size_t)L*2*DK, (size_t)L*L, scale, partial, nullptr, L, 32);

  // 5. denom = sum(partials) - (L - actulength)
  denom_k<<<dim3(B*L/256), 256, 0, stream>>>(partial, alen, denom, L, 32);

  // 6. out = (S @ V) / denom
  gemm256<2><<<dim3(8*4*8), 512, 0, stream>>>(
      S, VTb, nullptr, nullptr, out, nullptr, 8, 4, L, L, L, DV,
      (size_t)L*L, (size_t)DV*L, (size_t)L*DV, 1.f, nullptr, denom, L, 0);
}

// Round 5
// 300.860 us; speedup vs baseline: 1.4604x; 1.0347x over previous
//
#include <hip/hip_runtime.h>
#include <hip/hip_bf16.h>
#include <cstdint>

#define DEV __device__ __forceinline__

typedef __attribute__((ext_vector_type(8))) __bf16 bf16x8;
typedef __attribute__((ext_vector_type(4))) float f32x4;

DEV ushort f2bf(float f){
  uint32_t u = __builtin_bit_cast(uint32_t, f);
  u += 0x7fffu + ((u >> 16) & 1u);   // RNE
  return (ushort)(u >> 16);
}

DEV void gll16(const void* g, void* l){
  __builtin_amdgcn_global_load_lds((const __attribute__((address_space(1))) void*)g,
                                   (__attribute__((address_space(3))) void*)l, 16, 0, 0);
}

// ---------------------------------------------------------------------------
// 256x256 tile GEMM, C[M,N] = A[M,K] @ Bt[N,K]^T, bf16 in, f32 acc.
// 512 threads = 8 waves (2 M x 4 N), per-wave 128x64 output, K-slot = 32.
// LDS: 4-slot ring per matrix (128 KiB), XOR-swizzled (2-way = free, 0 confl).
// Schedule (r3-proven): 2 lockstep phases per slot, prefetch depth = 2 slots,
// tail vmcnt(4) counted (never drains mid-loop).
// Block mapping: XCD-contiguous chunks + 4x4 supertiles for L2 working set.
// MODE 0: C_bf16 = acc + bias[col]; bn>=8 writes V transposed to VTout
// MODE 1: C_bf16 = exp(acc*scale), f32 partial row sums (scores)
// MODE 2: C_f32  = acc / denom[row]          (PV)
// ---------------------------------------------------------------------------
template<int MODE>
__global__ __launch_bounds__(512, 2) void gemm256(
    const ushort* __restrict__ A, const ushort* __restrict__ Bt,
    const float* __restrict__ bias,
    ushort* __restrict__ Cb, float* __restrict__ Cf, ushort* __restrict__ VTout,
    int gm, int gn, int K, int lda, int ldb, int ldc,
    size_t sA, size_t sB, size_t sC,
    float scale, float* __restrict__ partial, const float* __restrict__ denom,
    int Mrows, int nch)
{
  __shared__ __align__(16) ushort As[4][128][64];
  __shared__ __align__(16) ushort Bs[4][128][64];

  const int tid  = threadIdx.x;
  const int lane = tid & 63, wid = tid >> 6;
  const int wm = wid >> 2, wn = wid & 3;
  const int lr = lane & 15, fq = lane >> 4;
  const int lrh = lr >> 1;
  const int lo2 = ((lane & 1) << 2) | fq;

  // XCD-aware block swizzle (all grids are multiples of 8): contiguous swz
  // range per XCD; then 4x4 supertiles so 16 co-resident blocks share
  // 4 A-panels + 4 B-panels (~4 MB ~= one XCD L2).
  const int nwg = gridDim.x;
  const int per = nwg >> 3;
  const int id  = blockIdx.x;
  const int swz = (id & 7) * per + (id >> 3);
  const int gmn = gm * gn;
  const int bz  = swz / gmn;
  const int rr  = swz - bz * gmn;
  const int q4  = rr >> 4, w4 = rr & 15;
  const int nsm = gm >> 2;
  const int stm = q4 % nsm, stn = q4 / nsm;
  const int bm  = (stm << 2) + (w4 & 3);
  const int bn  = (stn << 2) + (w4 >> 2);

  const ushort* Ab = A  + (size_t)bz * sA + (size_t)bm * 256 * (size_t)lda;
  const ushort* Bb = Bt + (size_t)bz * sB + (size_t)bn * 256 * (size_t)ldb;
  const int NT = K >> 5;   // K-slots of 32

  // ---- hoisted stage addressing ----
  // chunk c (16B): LDS linear dest c*16 within slot.
  // content swizzle: LDS[R][ci] holds G[2R + (u>>2)][kchunk u&3], u = ci^(R&7).
  auto srcOff = [&](int c, int ld)->size_t{
    int R = c >> 3, ci = c & 7, u = ci ^ (R & 7);
    return (size_t)(2*R + (u >> 2)) * (size_t)(ld*2) + (size_t)((u & 3) << 4);
  };
  const char* srcA0 = (const char*)Ab + srcOff(tid,       lda);
  const char* srcA1 = (const char*)Ab + srcOff(512 + tid, lda);
  const char* srcB0 = (const char*)Bb + srcOff(tid,       ldb);
  const char* srcB1 = (const char*)Bb + srcOff(512 + tid, ldb);
  char* AsB = (char*)As;
  char* BsB = (char*)Bs;
  const int dst0 = (wid << 6) * 16;          // wave-uniform; HW adds lane*16
  const int dst1 = (512 + (wid << 6)) * 16;

  auto stageA = [&](int t){
    const int sb = (t & 3) << 14;            // slot * 16384 B
    const size_t kb = (size_t)t << 6;        // t * 64 B along k
    gll16(srcA0 + kb, AsB + sb + dst0);
    gll16(srcA1 + kb, AsB + sb + dst1);
  };
  auto stageB = [&](int t){
    const int sb = (t & 3) << 14;
    const size_t kb = (size_t)t << 6;
    gll16(srcB0 + kb, BsB + sb + dst0);
    gll16(srcB1 + kb, BsB + sb + dst1);
  };

  f32x4 acc[8][4];
  const f32x4 z = {0.f, 0.f, 0.f, 0.f};
#pragma unroll
  for (int m = 0; m < 8; ++m)
#pragma unroll
    for (int n = 0; n < 4; ++n) acc[m][n] = z;

  // fragment ds_read offsets (ushort units); swizzled chunk lane-constant.
  const int cio  = (lo2 ^ lrh) << 3;
  const int aoff = (wm*64 + lrh)*64 + cio;
  const int boff = (wn*32 + lrh)*64 + cio;

  // prologue: slots 0,1 in flight (8 loads/thread)
  stageA(0); stageB(0); stageA(1); stageB(1);
  asm volatile("s_waitcnt vmcnt(4)" ::: "memory");   // slot 0 landed (mine)
  __builtin_amdgcn_s_barrier();                      // slot 0 landed (all)

  for (int t = 0; t < NT; ++t){
    const int s = t & 3;
    const ushort* Asl = (const ushort*)As + (size_t)s*8192;
    const ushort* Bsl = (const ushort*)Bs + (size_t)s*8192;
    const bool pre = (t + 2 < NT);

    // ---- phase 0: B-frags + A-frags m0-3, MFMA half m0-3 ----
    bf16x8 bfv[4], af0[4];
#pragma unroll
    for (int n = 0; n < 4; ++n)
      bfv[n] = *(const bf16x8*)&Bsl[boff + n*512];
#pragma unroll
    for (int m = 0; m < 4; ++m)
      af0[m] = *(const bf16x8*)&Asl[aoff + m*512];
    if (pre) stageA(t + 2);
    __builtin_amdgcn_s_barrier();
    asm volatile("s_waitcnt lgkmcnt(0)" ::: "memory");
    __builtin_amdgcn_sched_barrier(0);
    __builtin_amdgcn_s_setprio(1);
#pragma unroll
    for (int m = 0; m < 4; ++m)
#pragma unroll
      for (int n = 0; n < 4; ++n)
        acc[m][n] = __builtin_amdgcn_mfma_f32_16x16x32_bf16(af0[m], bfv[n], acc[m][n], 0, 0, 0);
    __builtin_amdgcn_s_setprio(0);
    __builtin_amdgcn_s_barrier();

    // ---- phase 1: A-frags m4-7, MFMA half m4-7 (B-frags reused) ----
    bf16x8 af1[4];
#pragma unroll
    for (int m = 0; m < 4; ++m)
      af1[m] = *(const bf16x8*)&Asl[aoff + (m + 4)*512];
    if (pre) stageB(t + 2);
    __builtin_amdgcn_s_barrier();
    asm volatile("s_waitcnt lgkmcnt(0)" ::: "memory");
    __builtin_amdgcn_sched_barrier(0);
    __builtin_amdgcn_s_setprio(1);
#pragma unroll
    for (int m = 0; m < 4; ++m)
#pragma unroll
      for (int n = 0; n < 4; ++n)
        acc[m + 4][n] = __builtin_amdgcn_mfma_f32_16x16x32_bf16(af1[m], bfv[n], acc[m + 4][n], 0, 0, 0);
    __builtin_amdgcn_s_setprio(0);

    // ---- slot tail: guarantee slot t+1 landed (counted; drains only at end) ----
    if (t < NT - 1){
      if (t + 2 < NT) asm volatile("s_waitcnt vmcnt(4)" ::: "memory");
      else            asm volatile("s_waitcnt vmcnt(0)" ::: "memory");
      __builtin_amdgcn_s_barrier();
    }
  }

  // ---------------- epilogue ----------------
  const int rbase = bm*256 + wm*128 + fq*4;
  const int cbase = bn*256 + wn*64 + lr;

  if (MODE == 0){
    if (bn >= 8){
      // V block: write transposed, VT[b][dv][l], contiguous ushort4 over l
#pragma unroll
      for (int m = 0; m < 8; ++m){
        int r0 = rbase + m*16;
        int b = r0 >> 11, l = r0 & 2047;
        ushort* vb = VTout + (size_t)b * 1024 * 2048;
#pragma unroll
        for (int n = 0; n < 4; ++n){
          int c = cbase + n*16;
          float bvv = bias[c];
          ushort4 u4;
          u4.x = f2bf(acc[m][n][0] + bvv);
          u4.y = f2bf(acc[m][n][1] + bvv);
          u4.z = f2bf(acc[m][n][2] + bvv);
          u4.w = f2bf(acc[m][n][3] + bvv);
          *(ushort4*)&vb[(size_t)(c - 2048)*2048 + l] = u4;
        }
      }
    } else {
      ushort* dst = Cb + (size_t)bz * sC;
#pragma unroll
      for (int m = 0; m < 8; ++m){
        int r0 = rbase + m*16;
#pragma unroll
        for (int n = 0; n < 4; ++n){
          int c = cbase + n*16;
          float bvv = bias[c];
#pragma unroll
          for (int i = 0; i < 4; ++i)
            dst[(size_t)(r0 + i)*ldc + c] = f2bf(acc[m][n][i] + bvv);
        }
      }
    }
  } else if (MODE == 1){
    ushort* dst = Cb + (size_t)bz * sC;
#pragma unroll
    for (int m = 0; m < 8; ++m){
      int r0 = rbase + m*16;
#pragma unroll
      for (int i = 0; i < 4; ++i){
        int r = r0 + i;
        float rs = 0.f;
#pragma unroll
        for (int n = 0; n < 4; ++n){
          float v = __expf(acc[m][n][i] * scale);
          dst[(size_t)r*ldc + cbase + n*16] = f2bf(v);
          rs += v;            // f32 sum from f32 exp values (NOT bf16-rounded)
        }
        rs += __shfl_xor(rs, 1);
        rs += __shfl_xor(rs, 2);
        rs += __shfl_xor(rs, 4);
        rs += __shfl_xor(rs, 8);
        if (lr == 0)
          partial[((size_t)bz*Mrows + r)*nch + (bn*4 + wn)] = rs;  // single writer
      }
    }
  } else {
    float* dst = Cf + (size_t)bz * sC;
#pragma unroll
    for (int m = 0; m < 8; ++m){
      int r0 = rbase + m*16;
#pragma unroll
      for (int i = 0; i < 4; ++i){
        int r = r0 + i;
        float inv = 1.0f / denom[(size_t)bz*Mrows + r];
#pragma unroll
        for (int n = 0; n < 4; ++n)
          dst[(size_t)r*ldc + cbase + n*16] = acc[m][n][i] * inv;
      }
    }
  }
}

// ---------------------------------------------------------------------------

__global__ void denom_k(const float* __restrict__ partial, const int* __restrict__ alen,
                        float* __restrict__ denom, int L, int nch){
  int i = blockIdx.x*blockDim.x + threadIdx.x;   // over B*L
  int b = i / L;
  const float* p = partial + (size_t)i*nch;
  float s = 0.f;
  for (int j = 0; j < nch; j++) s += p[j];
  denom[i] = s - (float)(L - alen[b]);
}

__global__ void cvt_f32_bf16(const float* __restrict__ in, ushort* __restrict__ out, long n4){
  long i = (long)blockIdx.x*blockDim.x + threadIdx.x;
  if (i >= n4) return;
  float4 f = ((const float4*)in)[i];
  ushort4 u;
  u.x = f2bf(f.x); u.y = f2bf(f.y); u.z = f2bf(f.z); u.w = f2bf(f.w);
  ((ushort4*)out)[i] = u;
}

// out[C,R] = in[R,C]^T with f32->bf16 convert. block (32,8)
__global__ __launch_bounds__(256) void transpose_f32_bf16(
    const float* __restrict__ in, ushort* __restrict__ out, int R, int C){
  __shared__ ushort t[32][33];
  int tx = threadIdx.x, ty = threadIdx.y;
  int c0 = blockIdx.x*32, r0 = blockIdx.y*32;
#pragma unroll
  for (int i = 0; i < 4; i++)
    t[ty + i*8][tx] = f2bf(in[(size_t)(r0 + ty + i*8)*C + c0 + tx]);
  __syncthreads();
#pragma unroll
  for (int i = 0; i < 4; i++)
    out[(size_t)(c0 + ty + i*8)*R + r0 + tx] = t[tx][ty + i*8];
}

__global__ void pack_bias(const float* __restrict__ q, const float* __restrict__ k,
                          const float* __restrict__ v, float* __restrict__ o){
  int i = blockIdx.x*blockDim.x + threadIdx.x;   // 3072
  o[i] = (i < 1024) ? q[i] : (i < 2048 ? k[i-1024] : v[i-2048]);
}

// ---------------------------------------------------------------------------

extern "C" void kernel_launch(void* const* d_in, const int* in_sizes, int n_in,
                              void* d_out, int out_size, void* d_ws, size_t ws_size,
                              hipStream_t stream){
  const int B = 8, L = 2048, D = 1024, DK = 1024, DV = 1024;
  const float scale = 0.03125f;  // 1/sqrt(1024)

  const float* x  = (const float*)d_in[0];
  const int* alen = (const int*)d_in[1];
  const float* Wq = (const float*)d_in[2];
  const float* bq = (const float*)d_in[3];
  const float* Wk = (const float*)d_in[4];
  const float* bk = (const float*)d_in[5];
  const float* Wv = (const float*)d_in[6];
  const float* bv = (const float*)d_in[7];
  float* out = (float*)d_out;

  char* ws = (char*)d_ws;
  size_t off = 0;
  auto alloc = [&](size_t bytes) -> void* {
    void* p = ws + off;
    off += (bytes + 255) & ~(size_t)255;
    return p;
  };
  ushort* xb     = (ushort*)alloc((size_t)B*L*D*2);        // 32 MB
  ushort* wqkvT  = (ushort*)alloc((size_t)3*DK*D*2);       // 6 MB
  float*  bqkv   = (float*)alloc((size_t)3*DK*4);
  ushort* QK     = (ushort*)alloc((size_t)B*L*2*DK*2);     // 67 MB (Q|K packed rows)
  ushort* VTb    = (ushort*)alloc((size_t)B*DV*L*2);       // 32 MB (V transposed)
  ushort* S      = (ushort*)alloc((size_t)B*L*L*2);        // 64 MB
  float* partial = (float*)alloc((size_t)B*L*32*4);        // 2 MB
  float* denom   = (float*)alloc((size_t)B*L*4);
  if (off > ws_size) return;

  dim3 tb(32, 8);

  // 1. x -> bf16
  long n4 = (long)B*L*D/4;
  cvt_f32_bf16<<<dim3((unsigned)((n4 + 255)/256)), 256, 0, stream>>>(x, xb, n4);

  // 2. packed W^T bf16 [3072][1024] + packed bias
  transpose_f32_bf16<<<dim3(DK/32, D/32), tb, 0, stream>>>(Wq, wqkvT,          D, DK);
  transpose_f32_bf16<<<dim3(DK/32, D/32), tb, 0, stream>>>(Wk, wqkvT + DK*D,   D, DK);
  transpose_f32_bf16<<<dim3(DV/32, D/32), tb, 0, stream>>>(Wv, wqkvT + 2*DK*D, D, DV);
  pack_bias<<<dim3(12), 256, 0, stream>>>(bq, bk, bv, bqkv);

  // 3. fused QKV projection: Q,K -> QK[B*L, 2048]; V -> VTb transposed
  gemm256<0><<<dim3(64*12), 512, 0, stream>>>(
      xb, wqkvT, bqkv, QK, nullptr, VTb, 64, 12, D, D, D, 2*DK,
      0, 0, 0, 0.f, nullptr, nullptr, 0, 0);

  // 4. scores: S = exp(scale * Q @ K^T), f32 partial row sums
  gemm256<1><<<dim3(8*8*8), 512, 0, stream>>>(
      QK /*Q*/, QK + DK /*K*/, nullptr, S, nullptr, nullptr, 8, 8, DK,
      2*DK, 2*DK, L,
      (size_t)L*2*DK, (size_t)L*2*DK, (size_t)L*L, scale, partial, nullptr, L, 32);

  // 5. denom = sum(partials) - (L - actulength)
  denom_k<<<dim3(B*L/256), 256, 0, stream>>>(partial, alen, denom, L, 32);

  // 6. out = (S @ V) / denom
  gemm256<2><<<dim3(8*4*8), 512, 0, stream>>>(
      S, VTb, nullptr, nullptr, out, nullptr, 8, 4, L, L, L, DV,
      (size_t)L*L, (size_t)DV*L, (size_t)L*DV, 1.f, nullptr, denom, L, 0);
}

// Round 6
// 299.734 us; speedup vs baseline: 1.4659x; 1.0038x over previous
//
#include <hip/hip_runtime.h>
#include <hip/hip_bf16.h>
#include <cstdint>

#define DEV __device__ __forceinline__

typedef __attribute__((ext_vector_type(8))) __bf16 bf16x8;
typedef __attribute__((ext_vector_type(4))) float f32x4;

DEV ushort f2bf(float f){
  uint32_t u = __builtin_bit_cast(uint32_t, f);
  u += 0x7fffu + ((u >> 16) & 1u);   // RNE
  return (ushort)(u >> 16);
}

DEV void gll16(const void* g, void* l){
  __builtin_amdgcn_global_load_lds((const __attribute__((address_space(1))) void*)g,
                                   (__attribute__((address_space(3))) void*)l, 16, 0, 0);
}

// ---------------------------------------------------------------------------
// 256x256 tile GEMM, C[M,N] = A[M,K] @ Bt[N,K]^T, bf16 in, f32 acc.
// 512 threads = 8 waves (2 M x 4 N), per-wave 128x64 output, K-slot = 32.
// LDS: 4-slot ring per matrix (128 KiB), XOR-swizzled (2-way = free, 0 confl).
// Schedule: 2 lockstep phases per slot, prefetch depth = 2 slots, tail
// vmcnt(4) counted. NO lgkmcnt(0)/sched_barrier pins before MFMA: ds_reads
// are compiler-visible, so fine-grained lgkmcnt lets early MFMAs overlap
// tail reads (m141: order-pinning regresses; m97 asm: compiler waits are
// near-optimal). s_barrier does not drain lgkm, so overlap survives it.
// Block mapping: XCD-contiguous chunks + 4x4 supertiles for L2 working set.
// MODE 0: C_bf16 = acc + bias[col]; bn>=8 writes V transposed to VTout
// MODE 1: C_bf16 = exp(acc*scale), f32 partial row sums (scores)
// MODE 2: C_f32  = acc / denom[row]          (PV)
// ---------------------------------------------------------------------------
template<int MODE>
__global__ __launch_bounds__(512, 2) void gemm256(
    const ushort* __restrict__ A, const ushort* __restrict__ Bt,
    const float* __restrict__ bias,
    ushort* __restrict__ Cb, float* __restrict__ Cf, ushort* __restrict__ VTout,
    int gm, int gn, int K, int lda, int ldb, int ldc,
    size_t sA, size_t sB, size_t sC,
    float scale, float* __restrict__ partial, const float* __restrict__ denom,
    int Mrows, int nch)
{
  __shared__ __align__(16) ushort As[4][128][64];
  __shared__ __align__(16) ushort Bs[4][128][64];

  const int tid  = threadIdx.x;
  const int lane = tid & 63, wid = tid >> 6;
  const int wm = wid >> 2, wn = wid & 3;
  const int lr = lane & 15, fq = lane >> 4;
  const int lrh = lr >> 1;
  const int lo2 = ((lane & 1) << 2) | fq;

  // XCD-aware block swizzle (all grids are multiples of 8): contiguous swz
  // range per XCD; then 4x4 supertiles so 16 co-resident blocks share
  // 4 A-panels + 4 B-panels (~4 MB ~= one XCD L2).
  const int nwg = gridDim.x;
  const int per = nwg >> 3;
  const int id  = blockIdx.x;
  const int swz = (id & 7) * per + (id >> 3);
  const int gmn = gm * gn;
  const int bz  = swz / gmn;
  const int rr  = swz - bz * gmn;
  const int q4  = rr >> 4, w4 = rr & 15;
  const int nsm = gm >> 2;
  const int stm = q4 % nsm, stn = q4 / nsm;
  const int bm  = (stm << 2) + (w4 & 3);
  const int bn  = (stn << 2) + (w4 >> 2);

  const ushort* Ab = A  + (size_t)bz * sA + (size_t)bm * 256 * (size_t)lda;
  const ushort* Bb = Bt + (size_t)bz * sB + (size_t)bn * 256 * (size_t)ldb;
  const int NT = K >> 5;   // K-slots of 32

  // ---- hoisted stage addressing ----
  // chunk c (16B): LDS linear dest c*16 within slot.
  // content swizzle: LDS[R][ci] holds G[2R + (u>>2)][kchunk u&3], u = ci^(R&7).
  auto srcOff = [&](int c, int ld)->size_t{
    int R = c >> 3, ci = c & 7, u = ci ^ (R & 7);
    return (size_t)(2*R + (u >> 2)) * (size_t)(ld*2) + (size_t)((u & 3) << 4);
  };
  const char* srcA0 = (const char*)Ab + srcOff(tid,       lda);
  const char* srcA1 = (const char*)Ab + srcOff(512 + tid, lda);
  const char* srcB0 = (const char*)Bb + srcOff(tid,       ldb);
  const char* srcB1 = (const char*)Bb + srcOff(512 + tid, ldb);
  char* AsB = (char*)As;
  char* BsB = (char*)Bs;
  const int dst0 = (wid << 6) * 16;          // wave-uniform; HW adds lane*16
  const int dst1 = (512 + (wid << 6)) * 16;

  auto stageA = [&](int t){
    const int sb = (t & 3) << 14;            // slot * 16384 B
    const size_t kb = (size_t)t << 6;        // t * 64 B along k
    gll16(srcA0 + kb, AsB + sb + dst0);
    gll16(srcA1 + kb, AsB + sb + dst1);
  };
  auto stageB = [&](int t){
    const int sb = (t & 3) << 14;
    const size_t kb = (size_t)t << 6;
    gll16(srcB0 + kb, BsB + sb + dst0);
    gll16(srcB1 + kb, BsB + sb + dst1);
  };

  f32x4 acc[8][4];
  const f32x4 z = {0.f, 0.f, 0.f, 0.f};
#pragma unroll
  for (int m = 0; m < 8; ++m)
#pragma unroll
    for (int n = 0; n < 4; ++n) acc[m][n] = z;

  // fragment ds_read offsets (ushort units); swizzled chunk lane-constant.
  const int cio  = (lo2 ^ lrh) << 3;
  const int aoff = (wm*64 + lrh)*64 + cio;
  const int boff = (wn*32 + lrh)*64 + cio;

  // prologue: slots 0,1 in flight (8 loads/thread)
  stageA(0); stageB(0); stageA(1); stageB(1);
  asm volatile("s_waitcnt vmcnt(4)" ::: "memory");   // slot 0 landed (mine)
  __builtin_amdgcn_s_barrier();                      // slot 0 landed (all)

  for (int t = 0; t < NT; ++t){
    const int s = t & 3;
    const ushort* Asl = (const ushort*)As + (size_t)s*8192;
    const ushort* Bsl = (const ushort*)Bs + (size_t)s*8192;
    const bool pre = (t + 2 < NT);

    // ---- phase 0: B-frags + A-frags m0-3, MFMA half m0-3 ----
    bf16x8 bfv[4], af0[4];
#pragma unroll
    for (int n = 0; n < 4; ++n)
      bfv[n] = *(const bf16x8*)&Bsl[boff + n*512];
#pragma unroll
    for (int m = 0; m < 4; ++m)
      af0[m] = *(const bf16x8*)&Asl[aoff + m*512];
    if (pre) stageA(t + 2);
    __builtin_amdgcn_s_barrier();
    // no lgkm pin: compiler emits fine-grained waits, MFMA overlaps tail reads
    __builtin_amdgcn_s_setprio(1);
#pragma unroll
    for (int m = 0; m < 4; ++m)
#pragma unroll
      for (int n = 0; n < 4; ++n)
        acc[m][n] = __builtin_amdgcn_mfma_f32_16x16x32_bf16(af0[m], bfv[n], acc[m][n], 0, 0, 0);
    __builtin_amdgcn_s_setprio(0);
    __builtin_amdgcn_s_barrier();

    // ---- phase 1: A-frags m4-7, MFMA half m4-7 (B-frags reused) ----
    bf16x8 af1[4];
#pragma unroll
    for (int m = 0; m < 4; ++m)
      af1[m] = *(const bf16x8*)&Asl[aoff + (m + 4)*512];
    if (pre) stageB(t + 2);
    __builtin_amdgcn_s_barrier();
    __builtin_amdgcn_s_setprio(1);
#pragma unroll
    for (int m = 0; m < 4; ++m)
#pragma unroll
      for (int n = 0; n < 4; ++n)
        acc[m + 4][n] = __builtin_amdgcn_mfma_f32_16x16x32_bf16(af1[m], bfv[n], acc[m + 4][n], 0, 0, 0);
    __builtin_amdgcn_s_setprio(0);

    // ---- slot tail: guarantee slot t+1 landed (counted; drains only at end) ----
    if (t < NT - 1){
      if (t + 2 < NT) asm volatile("s_waitcnt vmcnt(4)" ::: "memory");
      else            asm volatile("s_waitcnt vmcnt(0)" ::: "memory");
      __builtin_amdgcn_s_barrier();
    }
  }

  // ---------------- epilogue ----------------
  const int rbase = bm*256 + wm*128 + fq*4;
  const int cbase = bn*256 + wn*64 + lr;

  if (MODE == 0){
    if (bn >= 8){
      // V block: write transposed, VT[b][dv][l], contiguous ushort4 over l
#pragma unroll
      for (int m = 0; m < 8; ++m){
        int r0 = rbase + m*16;
        int b = r0 >> 11, l = r0 & 2047;
        ushort* vb = VTout + (size_t)b * 1024 * 2048;
#pragma unroll
        for (int n = 0; n < 4; ++n){
          int c = cbase + n*16;
          float bvv = bias[c];
          ushort4 u4;
          u4.x = f2bf(acc[m][n][0] + bvv);
          u4.y = f2bf(acc[m][n][1] + bvv);
          u4.z = f2bf(acc[m][n][2] + bvv);
          u4.w = f2bf(acc[m][n][3] + bvv);
          *(ushort4*)&vb[(size_t)(c - 2048)*2048 + l] = u4;
        }
      }
    } else {
      ushort* dst = Cb + (size_t)bz * sC;
#pragma unroll
      for (int m = 0; m < 8; ++m){
        int r0 = rbase + m*16;
#pragma unroll
        for (int n = 0; n < 4; ++n){
          int c = cbase + n*16;
          float bvv = bias[c];
#pragma unroll
          for (int i = 0; i < 4; ++i)
            dst[(size_t)(r0 + i)*ldc + c] = f2bf(acc[m][n][i] + bvv);
        }
      }
    }
  } else if (MODE == 1){
    ushort* dst = Cb + (size_t)bz * sC;
#pragma unroll
    for (int m = 0; m < 8; ++m){
      int r0 = rbase + m*16;
#pragma unroll
      for (int i = 0; i < 4; ++i){
        int r = r0 + i;
        float rs = 0.f;
#pragma unroll
        for (int n = 0; n < 4; ++n){
          float v = __expf(acc[m][n][i] * scale);
          dst[(size_t)r*ldc + cbase + n*16] = f2bf(v);
          rs += v;            // f32 sum from f32 exp values (NOT bf16-rounded)
        }
        rs += __shfl_xor(rs, 1);
        rs += __shfl_xor(rs, 2);
        rs += __shfl_xor(rs, 4);
        rs += __shfl_xor(rs, 8);
        if (lr == 0)
          partial[((size_t)bz*Mrows + r)*nch + (bn*4 + wn)] = rs;  // single writer
      }
    }
  } else {
    float* dst = Cf + (size_t)bz * sC;
#pragma unroll
    for (int m = 0; m < 8; ++m){
      int r0 = rbase + m*16;
#pragma unroll
      for (int i = 0; i < 4; ++i){
        int r = r0 + i;
        float inv = 1.0f / denom[(size_t)bz*Mrows + r];
#pragma unroll
        for (int n = 0; n < 4; ++n)
          dst[(size_t)r*ldc + cbase + n*16] = acc[m][n][i] * inv;
      }
    }
  }
}

// ---------------------------------------------------------------------------

__global__ void denom_k(const float* __restrict__ partial, const int* __restrict__ alen,
                        float* __restrict__ denom, int L, int nch){
  int i = blockIdx.x*blockDim.x + threadIdx.x;   // over B*L
  int b = i / L;
  const float* p = partial + (size_t)i*nch;
  float s = 0.f;
  for (int j = 0; j < nch; j++) s += p[j];
  denom[i] = s - (float)(L - alen[b]);
}

__global__ void cvt_f32_bf16(const float* __restrict__ in, ushort* __restrict__ out, long n4){
  long i = (long)blockIdx.x*blockDim.x + threadIdx.x;
  if (i >= n4) return;
  float4 f = ((const float4*)in)[i];
  ushort4 u;
  u.x = f2bf(f.x); u.y = f2bf(f.y); u.z = f2bf(f.z); u.w = f2bf(f.w);
  ((ushort4*)out)[i] = u;
}

// out[C,R] = in[R,C]^T with f32->bf16 convert. block (32,8)
__global__ __launch_bounds__(256) void transpose_f32_bf16(
    const float* __restrict__ in, ushort* __restrict__ out, int R, int C){
  __shared__ ushort t[32][33];
  int tx = threadIdx.x, ty = threadIdx.y;
  int c0 = blockIdx.x*32, r0 = blockIdx.y*32;
#pragma unroll
  for (int i = 0; i < 4; i++)
    t[ty + i*8][tx] = f2bf(in[(size_t)(r0 + ty + i*8)*C + c0 + tx]);
  __syncthreads();
#pragma unroll
  for (int i = 0; i < 4; i++)
    out[(size_t)(c0 + ty + i*8)*R + r0 + tx] = t[tx][ty + i*8];
}

__global__ void pack_bias(const float* __restrict__ q, const float* __restrict__ k,
                          const float* __restrict__ v, float* __restrict__ o){
  int i = blockIdx.x*blockDim.x + threadIdx.x;   // 3072
  o[i] = (i < 1024) ? q[i] : (i < 2048 ? k[i-1024] : v[i-2048]);
}

// ---------------------------------------------------------------------------

extern "C" void kernel_launch(void* const* d_in, const int* in_sizes, int n_in,
                              void* d_out, int out_size, void* d_ws, size_t ws_size,
                              hipStream_t stream){
  const int B = 8, L = 2048, D = 1024, DK = 1024, DV = 1024;
  const float scale = 0.03125f;  // 1/sqrt(1024)

  const float* x  = (const float*)d_in[0];
  const int* alen = (const int*)d_in[1];
  const float* Wq = (const float*)d_in[2];
  const float* bq = (const float*)d_in[3];
  const float* Wk = (const float*)d_in[4];
  const float* bk = (const float*)d_in[5];
  const float* Wv = (const float*)d_in[6];
  const float* bv = (const float*)d_in[7];
  float* out = (float*)d_out;

  char* ws = (char*)d_ws;
  size_t off = 0;
  auto alloc = [&](size_t bytes) -> void* {
    void* p = ws + off;
    off += (bytes + 255) & ~(size_t)255;
    return p;
  };
  ushort* xb     = (ushort*)alloc((size_t)B*L*D*2);        // 32 MB
  ushort* wqkvT  = (ushort*)alloc((size_t)3*DK*D*2);       // 6 MB
  float*  bqkv   = (float*)alloc((size_t)3*DK*4);
  ushort* QK     = (ushort*)alloc((size_t)B*L*2*DK*2);     // 67 MB (Q|K packed rows)
  ushort* VTb    = (ushort*)alloc((size_t)B*DV*L*2);       // 32 MB (V transposed)
  ushort* S      = (ushort*)alloc((size_t)B*L*L*2);        // 64 MB
  float* partial = (float*)alloc((size_t)B*L*32*4);        // 2 MB
  float* denom   = (float*)alloc((size_t)B*L*4);
  if (off > ws_size) return;

  dim3 tb(32, 8);

  // 1. x -> bf16
  long n4 = (long)B*L*D/4;
  cvt_f32_bf16<<<dim3((unsigned)((n4 + 255)/256)), 256, 0, stream>>>(x, xb, n4);

  // 2. packed W^T bf16 [3072][1024] + packed bias
  transpose_f32_bf16<<<dim3(DK/32, D/32), tb, 0, stream>>>(Wq, wqkvT,          D, DK);
  transpose_f32_bf16<<<dim3(DK/32, D/32), tb, 0, stream>>>(Wk, wqkvT + DK*D,   D, DK);
  transpose_f32_bf16<<<dim3(DV/32, D/32), tb, 0, stream>>>(Wv, wqkvT + 2*DK*D, D, DV);
  pack_bias<<<dim3(12), 256, 0, stream>>>(bq, bk, bv, bqkv);

  // 3. fused QKV projection: Q,K -> QK[B*L, 2048]; V -> VTb transposed
  gemm256<0><<<dim3(64*12), 512, 0, stream>>>(
      xb, wqkvT, bqkv, QK, nullptr, VTb, 64, 12, D, D, D, 2*DK,
      0, 0, 0, 0.f, nullptr, nullptr, 0, 0);

  // 4. scores: S = exp(scale * Q @ K^T), f32 partial row sums
  gemm256<1><<<dim3(8*8*8), 512, 0, stream>>>(
      QK /*Q*/, QK + DK /*K*/, nullptr, S, nullptr, nullptr, 8, 8, DK,
      2*DK, 2*DK, L,
      (size_t)L*2*DK, (size_t)L*2*DK, (size_t)L*L, scale, partial, nullptr, L, 32);

  // 5. denom = sum(partials) - (L - actulength)
  denom_k<<<dim3(B*L/256), 256, 0, stream>>>(partial, alen, denom, L, 32);

  // 6. out = (S @ V) / denom
  gemm256<2><<<dim3(8*4*8), 512, 0, stream>>>(
      S, VTb, nullptr, nullptr, out, nullptr, 8, 4, L, L, L, DV,
      (size_t)L*L, (size_t)DV*L, (size_t)L*DV, 1.f, nullptr, denom, L, 0);
}